// Round 6
// baseline (1935.466 us; speedup 1.0000x reference)
//
#include <hip/hip_runtime.h>
#include <hip/hip_bf16.h>
#include <hip/hip_fp16.h>

#define DT 0.1f
#define TAU_HP 12.3f
#define TAU_LP 2.3f
#define SCAN_B 1024

// Radix-build parameters: bucket = tgt >> BSHIFT (128 targets/bucket).
#define BSHIFT 7
#define BMASK 127
#define BMAX 2048          // max buckets supported (n_neurons <= 262144)
#define CHUNK 32768        // edges per block in hist/bin passes
#define B4_CAP 6144        // max records per bucket in finalize (mean 4096, +32 sigma)

// ---------------------------------------------------------------------------
// R1: atomics removed from steady state via CSR-by-target.
// R2: CSR-vector gather (coalesced, shfl reduce).
// R3: zero-global-atomic radix build (bhist->scan->bin->finalize).
// R4: fused step kernel (double-buffered v), Tm1-target edges dropped.
// R5: (a) edge storage split: srcs int[] + weights fp16[] = 6B/edge (was 8B);
//     (b) 8 lanes/row x 4 edges/lane (int4 + half4 loads);
//     (c) Tm1 rows get a dedicated compact thread range in the same launch;
//     (d) finalize reorders both arrays in-place via LDS.
// ---------------------------------------------------------------------------

__global__ void init_kernel(float* __restrict__ vA,
                            float* __restrict__ tm1_f,
                            int n_neurons, int n_tm1) {
    int i = blockIdx.x * blockDim.x + threadIdx.x;
    if (i < n_neurons) vA[i] = 0.0f;
    if (i < n_tm1) tm1_f[i] = 0.0f;
}

// --- build pass 1: per-(block,bucket) histogram (Tm1 targets dropped) --------
__global__ void bhist_kernel(const int* __restrict__ tgt, int* __restrict__ blkhist,
                             int n_edges, int n_tm1, int nb, int nblk) {
    __shared__ int hist[BMAX];
    int b = blockIdx.x;
    for (int i = threadIdx.x; i < nb; i += blockDim.x) hist[i] = 0;
    __syncthreads();
    int base = b * CHUNK;
    int end = min(base + CHUNK, n_edges);
    for (int k = base + threadIdx.x; k < end; k += blockDim.x) {
        int t = tgt[k];
        if (t >= n_tm1) atomicAdd(&hist[t >> BSHIFT], 1);
    }
    __syncthreads();
    for (int i = threadIdx.x; i < nb; i += blockDim.x)
        blkhist[(size_t)i * nblk + b] = hist[i];      // bucket-major for scan
}

// --- 3-level exclusive scan --------------------------------------------------
__global__ void scan1_kernel(const int* in, int* out, int* bsums, int n) {
    __shared__ int s[SCAN_B];
    int gid = blockIdx.x * SCAN_B + threadIdx.x;
    int x = (gid < n) ? in[gid] : 0;
    s[threadIdx.x] = x;
    __syncthreads();
    for (int off = 1; off < SCAN_B; off <<= 1) {
        int t = (threadIdx.x >= off) ? s[threadIdx.x - off] : 0;
        __syncthreads();
        s[threadIdx.x] += t;
        __syncthreads();
    }
    if (gid < n) out[gid] = s[threadIdx.x] - x;       // exclusive
    if (threadIdx.x == SCAN_B - 1) bsums[blockIdx.x] = s[SCAN_B - 1];
}

__global__ void scan2_kernel(int* bsums, int nb, int* total) {
    __shared__ int s[SCAN_B];
    int x = (threadIdx.x < nb) ? bsums[threadIdx.x] : 0;
    s[threadIdx.x] = x;
    __syncthreads();
    for (int off = 1; off < SCAN_B; off <<= 1) {
        int t = (threadIdx.x >= off) ? s[threadIdx.x - off] : 0;
        __syncthreads();
        s[threadIdx.x] += t;
        __syncthreads();
    }
    if (threadIdx.x == nb - 1) *total = s[threadIdx.x];   // inclusive grand total
    if (threadIdx.x < nb) bsums[threadIdx.x] = s[threadIdx.x] - x;
}

__global__ void scanadd_kernel(int* data, const int* __restrict__ bsums, int n) {
    int gid = blockIdx.x * blockDim.x + threadIdx.x;
    if (gid < n) data[gid] += bsums[gid / SCAN_B];
}

// --- build pass 2: bin kept edges into bucket order (LDS cursors) ------------
// srcs[pos] = src | tlow<<18 (tlow stripped in finalize); wh[pos] = fp16(w).
__global__ void bin_kernel(const int* __restrict__ src, const int* __restrict__ tgt,
                           const float* __restrict__ w, const int* __restrict__ scanned,
                           int* __restrict__ srcs_g, __half* __restrict__ wh_g,
                           int n_edges, int n_tm1, int nb, int nblk) {
    __shared__ int cur[BMAX];
    int b = blockIdx.x;
    for (int i = threadIdx.x; i < nb; i += blockDim.x)
        cur[i] = scanned[(size_t)i * nblk + b];
    __syncthreads();
    int base = b * CHUNK;
    int end = min(base + CHUNK, n_edges);
    for (int k = base + threadIdx.x; k < end; k += blockDim.x) {
        int t = tgt[k];
        if (t < n_tm1) continue;                      // dead edges (dv[:tm1]=0)
        int pos = atomicAdd(&cur[t >> BSHIFT], 1);    // LDS atomic
        srcs_g[pos] = src[k] | ((t & BMASK) << 18);
        wh_g[pos] = __float2half(w[k]);
    }
}

// --- build pass 3: per-bucket finalize, in-place via LDS ---------------------
__global__ void finalize_kernel(int* __restrict__ srcs_g, unsigned short* __restrict__ wh_g,
                                const int* __restrict__ scanned,
                                int* __restrict__ row_start,
                                const int* __restrict__ total,
                                int n_neurons, int nb, int nblk) {
    __shared__ int buf_s[B4_CAP];
    __shared__ unsigned short buf_w[B4_CAP];
    __shared__ int hist[BMASK + 1], ls[BMASK + 1], cur[BMASK + 1];
    int b = blockIdx.x;
    int n_kept = *total;
    int beg = scanned[(size_t)b * nblk];
    int end = (b == nb - 1) ? n_kept : scanned[(size_t)(b + 1) * nblk];
    int n = min(end - beg, B4_CAP);

    for (int k = threadIdx.x; k < n; k += blockDim.x) {
        buf_s[k] = srcs_g[beg + k];
        buf_w[k] = wh_g[beg + k];
    }
    if (threadIdx.x <= BMASK) hist[threadIdx.x] = 0;
    __syncthreads();
    for (int k = threadIdx.x; k < n; k += blockDim.x)
        atomicAdd(&hist[(buf_s[k] >> 18) & BMASK], 1);
    __syncthreads();
    if (threadIdx.x <= BMASK) ls[threadIdx.x] = hist[threadIdx.x];
    __syncthreads();
    for (int off = 1; off <= BMASK; off <<= 1) {
        int t = (threadIdx.x <= BMASK && threadIdx.x >= off) ? ls[threadIdx.x - off] : 0;
        __syncthreads();
        if (threadIdx.x <= BMASK) ls[threadIdx.x] += t;   // inclusive
        __syncthreads();
    }
    if (threadIdx.x <= BMASK) {
        int excl = ls[threadIdx.x] - hist[threadIdx.x];
        cur[threadIdx.x] = excl;
        int t = (b << BSHIFT) + threadIdx.x;
        if (t < n_neurons) row_start[t] = beg + excl;
    }
    if (b == nb - 1 && threadIdx.x == 0) row_start[n_neurons] = n_kept;
    __syncthreads();
    for (int k = threadIdx.x; k < n; k += blockDim.x) {
        int pos = atomicAdd(&cur[(buf_s[k] >> 18) & BMASK], 1);  // LDS atomic
        srcs_g[beg + pos] = buf_s[k] & 0x3FFFF;
        wh_g[beg + pos] = buf_w[k];
    }
}

// --- fused per-step kernel ---------------------------------------------------
// Thread range [0, tm1_pad): Tm1 rows (filters, 1 thread/row).
// Thread range [tm1_pad, ...): gather rows, 8 lanes/row, 4 edges/lane/iter.
__global__ void step_kernel(const int* __restrict__ row_start,
                            const int* __restrict__ srcs,
                            const __half* __restrict__ wh,
                            const float* __restrict__ vr,
                            float* __restrict__ vw,
                            float* __restrict__ tm1_f,
                            const float* __restrict__ x,     // tm1_input + k*n_tm1
                            const float* __restrict__ tau,
                            const float* __restrict__ vrest,
                            int n_neurons, int n_tm1, int tm1_pad, int last) {
    int tid = blockIdx.x * blockDim.x + threadIdx.x;

    if (tid < tm1_pad) {
        int row = tid;
        if (row < n_tm1) {
            float cur = vr[row];                 // = tm1_v at step k
            if (last) {
                vw[row] = cur;                   // ref: v[:tm1] = old tm1_v
            } else {
                float f  = tm1_f[row];
                float xk = x[row];
                tm1_f[row] = f + DT * (xk - f) / TAU_HP;
                vw[row] = cur + DT * (fmaxf(xk - f, 0.0f) - cur) / TAU_LP;
            }
        }
        return;
    }

    int t2   = tid - tm1_pad;
    int row  = n_tm1 + (t2 >> 3);
    int lane = t2 & 7;
    if (row >= n_neurons) return;

    int s = row_start[row];
    int e = row_start[row + 1];
    float sum = 0.0f;
    for (int p = (s & ~3) + 4 * lane; p < e; p += 32) {
        int4 q = *(const int4*)(srcs + p);               // 16B aligned (p%4==0)
        float2 wq = *(const float2*)(wh + p);            // 4 halves, 8B aligned
        float2 f01 = __half22float2(__builtin_bit_cast(__half2, wq.x));
        float2 f23 = __half22float2(__builtin_bit_cast(__half2, wq.y));
        if (p >= s)              sum += fmaxf(vr[q.x], 0.0f) * f01.x;
        if (p + 1 >= s && p + 1 < e) sum += fmaxf(vr[q.y], 0.0f) * f01.y;
        if (p + 2 >= s && p + 2 < e) sum += fmaxf(vr[q.z], 0.0f) * f23.x;
        if (p + 3 < e)           sum += fmaxf(vr[q.w], 0.0f) * f23.y;
    }
    sum += __shfl_xor(sum, 4);
    sum += __shfl_xor(sum, 2);
    sum += __shfl_xor(sum, 1);
    if (lane == 0) {
        float vi = vr[row];
        vw[row] = vi + DT * ((-vi + sum + vrest[row]) / tau[row]);
    }
}

extern "C" void kernel_launch(void* const* d_in, const int* in_sizes, int n_in,
                              void* d_out, int out_size, void* d_ws, size_t ws_size,
                              hipStream_t stream) {
    const float* tm1_input  = (const float*)d_in[0];
    const float* weights    = (const float*)d_in[1];
    const float* tau        = (const float*)d_in[2];
    const float* vrest      = (const float*)d_in[3];
    const int*   source_idx = (const int*)d_in[4];
    const int*   target_idx = (const int*)d_in[5];

    const int n_edges   = in_sizes[1];
    const int n_neurons = in_sizes[2];
    const int n_tm1     = 25000;
    const int steps     = in_sizes[0] / n_tm1;

    const int nb   = (n_neurons + BMASK) >> BSHIFT;          // 1563 buckets
    const int nblk = (n_edges + CHUNK - 1) / CHUNK;          // 196 blocks
    const int n_scan = nb * nblk;                            // 306,348

    // Workspace (4-byte units). srcs first -> 16B aligned for int4 gather.
    size_t off = 0;
    auto alloc = [&](size_t n) { size_t o = off; off += n; return o; };
    int* ws_i = (int*)d_ws;
    float* ws_f = (float*)d_ws;

    int*    srcs      = ws_i + alloc(((size_t)n_edges + 8 + 3) & ~(size_t)3);
    __half* wh        = (__half*)(ws_i + alloc(((size_t)n_edges + 8 + 1) / 2));
    float*  vA        = ws_f + alloc(n_neurons);
    float*  vB        = ws_f + alloc(n_neurons);
    float*  tm1_f     = ws_f + alloc(n_tm1);
    int*    row_start = ws_i + alloc(n_neurons + 1);
    int*    blkhist   = ws_i + alloc((size_t)n_scan);
    int*    bsums     = ws_i + alloc(SCAN_B);
    int*    total     = ws_i + alloc(1);
    (void)ws_size;

    float* out = (float*)d_out;

    const int B = 256;
    const int gridN = (n_neurons + B - 1) / B;
    const int nScanBlocks = (n_scan + SCAN_B - 1) / SCAN_B;  // 300 <= 1024
    const int gridSA = (n_scan + B - 1) / B;

    const int tm1_pad = ((n_tm1 + B - 1) / B) * B;           // 25600
    const long long total_threads = (long long)tm1_pad + (long long)(n_neurons - n_tm1) * 8;
    const int gridS = (int)((total_threads + B - 1) / B);

    // --- one-time (per launch) CSR build: zero global atomics ---
    init_kernel<<<gridN, B, 0, stream>>>(vA, tm1_f, n_neurons, n_tm1);
    bhist_kernel<<<nblk, 1024, 0, stream>>>(target_idx, blkhist, n_edges, n_tm1,
                                            nb, nblk);
    scan1_kernel<<<nScanBlocks, SCAN_B, 0, stream>>>(blkhist, blkhist, bsums, n_scan);
    scan2_kernel<<<1, SCAN_B, 0, stream>>>(bsums, nScanBlocks, total);
    scanadd_kernel<<<gridSA, B, 0, stream>>>(blkhist, bsums, n_scan);
    bin_kernel<<<nblk, 1024, 0, stream>>>(source_idx, target_idx, weights, blkhist,
                                          srcs, wh, n_edges, n_tm1, nb, nblk);
    finalize_kernel<<<nb, 1024, 0, stream>>>(srcs, (unsigned short*)wh, blkhist,
                                             row_start, total, n_neurons, nb, nblk);

    // --- steps: ONE fused kernel per step, double-buffered v ---
    for (int k = 0; k < steps; ++k) {
        const float* vr = (k & 1) ? vB : vA;
        float* vw = (k == steps - 1) ? out : ((k & 1) ? vA : vB);
        step_kernel<<<gridS, B, 0, stream>>>(
            row_start, srcs, wh, vr, vw, tm1_f,
            tm1_input + (size_t)k * n_tm1,
            tau, vrest, n_neurons, n_tm1, tm1_pad, (k == steps - 1) ? 1 : 0);
    }
}

// Round 7
// 1912.954 us; speedup vs baseline: 1.0118x; 1.0118x over previous
//
#include <hip/hip_runtime.h>
#include <hip/hip_bf16.h>

#define DT 0.1f
#define TAU_HP 12.3f
#define TAU_LP 2.3f
#define SCAN_B 1024

// Radix-build parameters: bucket = tgt >> BSHIFT (128 targets/bucket).
#define BSHIFT 7
#define BMASK 127
#define BMAX 2048          // max buckets supported (n_neurons <= 262144)
#define CHUNK 65536        // edges per block in hist/bin passes
#define B4_CAP 6144        // max records per bucket in finalize

// ---------------------------------------------------------------------------
// R1: atomics removed from steady state via CSR-by-target.
// R2: CSR-vector gather (coalesced, shfl reduce).
// R3: zero-global-atomic radix build (bhist->scan->bin->finalize).
// R4: fused step kernel (double-buffered v), Tm1-target edges dropped.
// R5: 8 lanes/row x 4 edges/lane; compact Tm1 thread range.
// R6 (this): REVERT split srcs/fp16 layout (bin write-amp 150->262MB, -100us)
//     back to single int2 (src|tlow, w fp32) stream. CHUNK 65536 for longer
//     scatter bursts. Grid-stride persistent step kernel (2048 blocks).
// ---------------------------------------------------------------------------

__global__ void init_kernel(float* __restrict__ vA,
                            float* __restrict__ tm1_f,
                            int n_neurons, int n_tm1) {
    int i = blockIdx.x * blockDim.x + threadIdx.x;
    if (i < n_neurons) vA[i] = 0.0f;
    if (i < n_tm1) tm1_f[i] = 0.0f;
}

// --- build pass 1: per-(block,bucket) histogram (Tm1 targets dropped) --------
__global__ void bhist_kernel(const int* __restrict__ tgt, int* __restrict__ blkhist,
                             int n_edges, int n_tm1, int nb, int nblk) {
    __shared__ int hist[BMAX];
    int b = blockIdx.x;
    for (int i = threadIdx.x; i < nb; i += blockDim.x) hist[i] = 0;
    __syncthreads();
    int base = b * CHUNK;
    int end = min(base + CHUNK, n_edges);
    for (int k = base + threadIdx.x; k < end; k += blockDim.x) {
        int t = tgt[k];
        if (t >= n_tm1) atomicAdd(&hist[t >> BSHIFT], 1);
    }
    __syncthreads();
    for (int i = threadIdx.x; i < nb; i += blockDim.x)
        blkhist[(size_t)i * nblk + b] = hist[i];      // bucket-major for scan
}

// --- 3-level exclusive scan --------------------------------------------------
__global__ void scan1_kernel(const int* in, int* out, int* bsums, int n) {
    __shared__ int s[SCAN_B];
    int gid = blockIdx.x * SCAN_B + threadIdx.x;
    int x = (gid < n) ? in[gid] : 0;
    s[threadIdx.x] = x;
    __syncthreads();
    for (int off = 1; off < SCAN_B; off <<= 1) {
        int t = (threadIdx.x >= off) ? s[threadIdx.x - off] : 0;
        __syncthreads();
        s[threadIdx.x] += t;
        __syncthreads();
    }
    if (gid < n) out[gid] = s[threadIdx.x] - x;       // exclusive
    if (threadIdx.x == SCAN_B - 1) bsums[blockIdx.x] = s[SCAN_B - 1];
}

__global__ void scan2_kernel(int* bsums, int nb, int* total) {
    __shared__ int s[SCAN_B];
    int x = (threadIdx.x < nb) ? bsums[threadIdx.x] : 0;
    s[threadIdx.x] = x;
    __syncthreads();
    for (int off = 1; off < SCAN_B; off <<= 1) {
        int t = (threadIdx.x >= off) ? s[threadIdx.x - off] : 0;
        __syncthreads();
        s[threadIdx.x] += t;
        __syncthreads();
    }
    if (threadIdx.x == nb - 1) *total = s[threadIdx.x];   // inclusive grand total
    if (threadIdx.x < nb) bsums[threadIdx.x] = s[threadIdx.x] - x;
}

__global__ void scanadd_kernel(int* data, const int* __restrict__ bsums, int n) {
    int gid = blockIdx.x * blockDim.x + threadIdx.x;
    if (gid < n) data[gid] += bsums[gid / SCAN_B];
}

// --- build pass 2: bin kept edges into bucket order (LDS cursors) ------------
// record = (src | tlow<<18, weight-bits); src < 2^18, tlow 7 bits.
__global__ void bin_kernel(const int* __restrict__ src, const int* __restrict__ tgt,
                           const float* __restrict__ w, const int* __restrict__ scanned,
                           int2* __restrict__ edges, int n_edges, int n_tm1,
                           int nb, int nblk) {
    __shared__ int cur[BMAX];
    int b = blockIdx.x;
    for (int i = threadIdx.x; i < nb; i += blockDim.x)
        cur[i] = scanned[(size_t)i * nblk + b];
    __syncthreads();
    int base = b * CHUNK;
    int end = min(base + CHUNK, n_edges);
    for (int k = base + threadIdx.x; k < end; k += blockDim.x) {
        int t = tgt[k];
        if (t < n_tm1) continue;                      // dead edges (dv[:tm1]=0)
        int pos = atomicAdd(&cur[t >> BSHIFT], 1);    // LDS atomic
        edges[pos] = make_int2(src[k] | ((t & BMASK) << 18), __float_as_int(w[k]));
    }
}

// --- build pass 3: per-bucket finalize, entirely in LDS, in-place ------------
__global__ void finalize_kernel(int2* edges, const int* __restrict__ scanned,
                                int* __restrict__ row_start,
                                const int* __restrict__ total,
                                int n_neurons, int nb, int nblk) {
    __shared__ int2 buf[B4_CAP];
    __shared__ int hist[BMASK + 1], ls[BMASK + 1], cur[BMASK + 1];
    int b = blockIdx.x;
    int n_kept = *total;
    int beg = scanned[(size_t)b * nblk];
    int end = (b == nb - 1) ? n_kept : scanned[(size_t)(b + 1) * nblk];
    int n = min(end - beg, B4_CAP);

    for (int k = threadIdx.x; k < n; k += blockDim.x) buf[k] = edges[beg + k];
    if (threadIdx.x <= BMASK) hist[threadIdx.x] = 0;
    __syncthreads();
    for (int k = threadIdx.x; k < n; k += blockDim.x)
        atomicAdd(&hist[(buf[k].x >> 18) & BMASK], 1);
    __syncthreads();
    if (threadIdx.x <= BMASK) ls[threadIdx.x] = hist[threadIdx.x];
    __syncthreads();
    for (int off = 1; off <= BMASK; off <<= 1) {
        int t = (threadIdx.x <= BMASK && threadIdx.x >= off) ? ls[threadIdx.x - off] : 0;
        __syncthreads();
        if (threadIdx.x <= BMASK) ls[threadIdx.x] += t;   // inclusive
        __syncthreads();
    }
    if (threadIdx.x <= BMASK) {
        int excl = ls[threadIdx.x] - hist[threadIdx.x];
        cur[threadIdx.x] = excl;
        int t = (b << BSHIFT) + threadIdx.x;
        if (t < n_neurons) row_start[t] = beg + excl;
    }
    if (b == nb - 1 && threadIdx.x == 0) row_start[n_neurons] = n_kept;
    __syncthreads();
    for (int k = threadIdx.x; k < n; k += blockDim.x) {
        int2 r = buf[k];
        int pos = atomicAdd(&cur[(r.x >> 18) & BMASK], 1);  // LDS atomic
        edges[beg + pos] = make_int2(r.x & 0x3FFFF, r.y);
    }
}

// --- fused per-step kernel (grid-stride persistent) --------------------------
// Virtual-tid range [0, tm1_pad): Tm1 rows (filters, 1 thread/row).
// Range [tm1_pad, ...): gather rows, 8 lanes/row, 4 edges/lane/iter.
// tm1_pad is wave-aligned so each 8-lane octet maps to exactly one row.
__global__ void step_kernel(const int* __restrict__ row_start,
                            const int2* __restrict__ edges,
                            const float* __restrict__ vr,
                            float* __restrict__ vw,
                            float* __restrict__ tm1_f,
                            const float* __restrict__ x,     // tm1_input + k*n_tm1
                            const float* __restrict__ tau,
                            const float* __restrict__ vrest,
                            int n_neurons, int n_tm1, int tm1_pad,
                            int total_threads, int last) {
    int stride = gridDim.x * blockDim.x;
    for (int tid = blockIdx.x * blockDim.x + threadIdx.x; tid < total_threads;
         tid += stride) {
        if (tid < tm1_pad) {
            int row = tid;
            if (row < n_tm1) {
                float cur = vr[row];                 // = tm1_v at step k
                if (last) {
                    vw[row] = cur;                   // ref: v[:tm1] = old tm1_v
                } else {
                    float f  = tm1_f[row];
                    float xk = x[row];
                    tm1_f[row] = f + DT * (xk - f) / TAU_HP;
                    vw[row] = cur + DT * (fmaxf(xk - f, 0.0f) - cur) / TAU_LP;
                }
            }
            continue;
        }

        int t2   = tid - tm1_pad;
        int row  = n_tm1 + (t2 >> 3);
        int lane = t2 & 7;

        int s = row_start[row];
        int e = row_start[row + 1];
        float sum = 0.0f;
        for (int p = (s & ~3) + 4 * lane; p < e; p += 32) {
            int4 a = *(const int4*)(edges + p);       // edges p, p+1 (16B aligned)
            int4 b = *(const int4*)(edges + p + 2);   // edges p+2, p+3
            if (p >= s)                  sum += fmaxf(vr[a.x], 0.0f) * __int_as_float(a.y);
            if (p + 1 >= s && p + 1 < e) sum += fmaxf(vr[a.z], 0.0f) * __int_as_float(a.w);
            if (p + 2 >= s && p + 2 < e) sum += fmaxf(vr[b.x], 0.0f) * __int_as_float(b.y);
            if (p + 3 < e)               sum += fmaxf(vr[b.z], 0.0f) * __int_as_float(b.w);
        }
        sum += __shfl_xor(sum, 4);
        sum += __shfl_xor(sum, 2);
        sum += __shfl_xor(sum, 1);
        if (lane == 0) {
            float vi = vr[row];
            vw[row] = vi + DT * ((-vi + sum + vrest[row]) / tau[row]);
        }
    }
}

extern "C" void kernel_launch(void* const* d_in, const int* in_sizes, int n_in,
                              void* d_out, int out_size, void* d_ws, size_t ws_size,
                              hipStream_t stream) {
    const float* tm1_input  = (const float*)d_in[0];
    const float* weights    = (const float*)d_in[1];
    const float* tau        = (const float*)d_in[2];
    const float* vrest      = (const float*)d_in[3];
    const int*   source_idx = (const int*)d_in[4];
    const int*   target_idx = (const int*)d_in[5];

    const int n_edges   = in_sizes[1];
    const int n_neurons = in_sizes[2];
    const int n_tm1     = 25000;
    const int steps     = in_sizes[0] / n_tm1;

    const int nb   = (n_neurons + BMASK) >> BSHIFT;          // 1563 buckets
    const int nblk = (n_edges + CHUNK - 1) / CHUNK;          // 98 blocks
    const int n_scan = nb * nblk;                            // 153,174

    // Workspace (4-byte units). edges first -> 16B aligned for int4 gather.
    size_t off = 0;
    auto alloc = [&](size_t n) { size_t o = off; off += n; return o; };
    int* ws_i = (int*)d_ws;
    float* ws_f = (float*)d_ws;

    int2*  edges     = (int2*)(ws_i + alloc((size_t)(n_edges + 8) * 2));
    float* vA        = ws_f + alloc(n_neurons);
    float* vB        = ws_f + alloc(n_neurons);
    float* tm1_f     = ws_f + alloc(n_tm1);
    int*   row_start = ws_i + alloc(n_neurons + 1);
    int*   blkhist   = ws_i + alloc((size_t)n_scan);
    int*   bsums     = ws_i + alloc(SCAN_B);
    int*   total     = ws_i + alloc(1);
    (void)ws_size;

    float* out = (float*)d_out;

    const int B = 256;
    const int gridN = (n_neurons + B - 1) / B;
    const int nScanBlocks = (n_scan + SCAN_B - 1) / SCAN_B;  // 150 <= 1024
    const int gridSA = (n_scan + B - 1) / B;

    const int tm1_pad = ((n_tm1 + 63) / 64) * 64;            // 25024? -> wave-aligned
    const int total_threads = tm1_pad + (n_neurons - n_tm1) * 8;
    const int gridS = 2048;                                  // persistent grid-stride

    // --- one-time (per launch) CSR build: zero global atomics ---
    init_kernel<<<gridN, B, 0, stream>>>(vA, tm1_f, n_neurons, n_tm1);
    bhist_kernel<<<nblk, 1024, 0, stream>>>(target_idx, blkhist, n_edges, n_tm1,
                                            nb, nblk);
    scan1_kernel<<<nScanBlocks, SCAN_B, 0, stream>>>(blkhist, blkhist, bsums, n_scan);
    scan2_kernel<<<1, SCAN_B, 0, stream>>>(bsums, nScanBlocks, total);
    scanadd_kernel<<<gridSA, B, 0, stream>>>(blkhist, bsums, n_scan);
    bin_kernel<<<nblk, 1024, 0, stream>>>(source_idx, target_idx, weights, blkhist,
                                          edges, n_edges, n_tm1, nb, nblk);
    finalize_kernel<<<nb, 1024, 0, stream>>>(edges, blkhist, row_start, total,
                                             n_neurons, nb, nblk);

    // --- steps: ONE fused kernel per step, double-buffered v ---
    for (int k = 0; k < steps; ++k) {
        const float* vr = (k & 1) ? vB : vA;
        float* vw = (k == steps - 1) ? out : ((k & 1) ? vA : vB);
        step_kernel<<<gridS, B, 0, stream>>>(
            row_start, edges, vr, vw, tm1_f,
            tm1_input + (size_t)k * n_tm1,
            tau, vrest, n_neurons, n_tm1, tm1_pad, total_threads,
            (k == steps - 1) ? 1 : 0);
    }
}